// Round 1
// baseline (351.211 us; speedup 1.0000x reference)
//
#include <hip/hip_runtime.h>

#define DEV __device__ __forceinline__

typedef __attribute__((ext_vector_type(8))) short bf16x8;
typedef __attribute__((ext_vector_type(4))) float f32x4;

#define MFMA(a, b, c) __builtin_amdgcn_mfma_f32_16x16x32_bf16(a, b, c, 0, 0, 0)

// sizes (fixed problem)
#define BS 2
#define S 2048
#define DM 768
#define NH 8
#define DK 64
#define NPROJ 512   // NH*DK
#define BH 16       // BS*NH

DEV unsigned short f2bf(float f) {
    unsigned int u = __float_as_uint(f);
    unsigned int r = u + 0x7fffu + ((u >> 16) & 1u);
    return (unsigned short)(r >> 16);
}

DEV bf16x8 pack8(float4 f0, float4 f1) {
    bf16x8 r;
    r[0] = (short)f2bf(f0.x); r[1] = (short)f2bf(f0.y);
    r[2] = (short)f2bf(f0.z); r[3] = (short)f2bf(f0.w);
    r[4] = (short)f2bf(f1.x); r[5] = (short)f2bf(f1.y);
    r[6] = (short)f2bf(f1.z); r[7] = (short)f2bf(f1.w);
    return r;
}

DEV float redsum16(float v) {
    v += __shfl_xor(v, 1);
    v += __shfl_xor(v, 2);
    v += __shfl_xor(v, 4);
    v += __shfl_xor(v, 8);
    return v;
}

// ---------- mask (bool bytes) -> bitmask, 64 cols per u64 word ----------
__global__ __launch_bounds__(256) void k_mask_bits(const unsigned char* __restrict__ mask,
                                                   unsigned long long* __restrict__ bits) {
    int w = blockIdx.x * 256 + threadIdx.x;  // word index < BS*S*(S/64) = 131072
    const unsigned long long* m8 = (const unsigned long long*)(mask + (size_t)w * 64);
    unsigned long long out = 0ull;
#pragma unroll
    for (int i = 0; i < 8; i++) {
        unsigned long long x = m8[i];
#pragma unroll
        for (int k = 0; k < 8; k++)
            if ((x >> (8 * k)) & 0xffull) out |= 1ull << (i * 8 + k);
    }
    bits[w] = out;
}

// ---------- W transpose + cast: in fp32 [R][C] -> out bf16 [C][R], *scale ----------
__global__ __launch_bounds__(256) void k_transpose_w(const float* __restrict__ in,
                                                     unsigned short* __restrict__ out,
                                                     int R, int C, float scale) {
    __shared__ float t[32][33];
    int c0 = blockIdx.x * 32, r0 = blockIdx.y * 32;
    int tx = threadIdx.x, ty = threadIdx.y;  // (32,8)
#pragma unroll
    for (int i = 0; i < 4; i++) {
        int r = ty * 4 + i;
        t[r][tx] = in[(size_t)(r0 + r) * C + c0 + tx];
    }
    __syncthreads();
#pragma unroll
    for (int i = 0; i < 4; i++) {
        int cc = ty * 4 + i;
        out[(size_t)(c0 + cc) * R + r0 + tx] = f2bf(t[tx][cc] * scale);
    }
}

// ---------- projection GEMM: A(fp32 4096x768) x BT(bf16 512x768) -> head-split bf16 ----------
__global__ __launch_bounds__(256) void k_proj(
    const float* __restrict__ Aq, const float* __restrict__ Ak, const float* __restrict__ Av,
    const unsigned short* __restrict__ WqT, const unsigned short* __restrict__ WkT,
    const unsigned short* __restrict__ WvT,
    unsigned short* __restrict__ Qh, unsigned short* __restrict__ Kh,
    unsigned short* __restrict__ Vh) {
    const int p = blockIdx.z;
    const float* A = (p == 0) ? Aq : ((p == 1) ? Ak : Av);
    const unsigned short* BT = (p == 0) ? WqT : ((p == 1) ? WkT : WvT);
    unsigned short* O = (p == 0) ? Qh : ((p == 1) ? Kh : Vh);

    const int wave = threadIdx.x >> 6, lane = threadIdx.x & 63;
    const int lr = lane & 15, lg = lane >> 4;
    const int arow = blockIdx.x * 64 + wave * 16 + lr;

    f32x4 zero = {0.f, 0.f, 0.f, 0.f};
    f32x4 acc[4] = {zero, zero, zero, zero};

    const float* ap = A + (size_t)arow * DM + lg * 8;
#pragma unroll 4
    for (int ks = 0; ks < DM / 32; ks++) {
        float4 f0 = *(const float4*)(ap);
        float4 f1 = *(const float4*)(ap + 4);
        ap += 32;
        bf16x8 a = pack8(f0, f1);
#pragma unroll
        for (int nt = 0; nt < 4; nt++) {
            int bn = blockIdx.y * 64 + nt * 16 + lr;
            bf16x8 b = *(const bf16x8*)(BT + (size_t)bn * DM + ks * 32 + lg * 8);
            acc[nt] = MFMA(a, b, acc[nt]);
        }
    }
#pragma unroll
    for (int nt = 0; nt < 4; nt++) {
        int col = blockIdx.y * 64 + nt * 16 + lr;
        int h = col >> 6, d = col & 63;
#pragma unroll
        for (int j = 0; j < 4; j++) {
            int r = blockIdx.x * 64 + wave * 16 + lg * 4 + j;
            int bb = r >> 11, s = r & 2047;
            O[(((size_t)bb * NH + h) * S + s) * DK + d] = f2bf(acc[nt][j]);
        }
    }
}

// ---------- V transpose per head: bf16 [bh][S][64] -> [bh][64][S] ----------
__global__ __launch_bounds__(256) void k_transpose_v(const unsigned short* __restrict__ in,
                                                     unsigned short* __restrict__ out) {
    __shared__ unsigned short t[64][66];
    int bh = blockIdx.y;
    int s0 = blockIdx.x * 64;
    int tid = threadIdx.x;
    const unsigned short* ip = in + ((size_t)bh * S + s0) * DK;
#pragma unroll
    for (int i = 0; i < 16; i++) {
        int lin = i * 256 + tid;
        int r = lin >> 6, c = lin & 63;
        t[r][c] = ip[r * DK + c];
    }
    __syncthreads();
    unsigned short* op = out + (size_t)bh * DK * S + s0;
#pragma unroll
    for (int i = 0; i < 16; i++) {
        int lin = i * 256 + tid;
        int d = lin >> 6, sc = lin & 63;
        op[(size_t)d * S + sc] = t[sc][d];
    }
}

// ---------- fused attention: scores -> softmax weights (to d_out) -> PV ctx ----------
__global__ __launch_bounds__(256) void k_attn(
    const unsigned short* __restrict__ Qh, const unsigned short* __restrict__ Kh,
    const unsigned short* __restrict__ VhT, const unsigned long long* __restrict__ mbits,
    float* __restrict__ wout, unsigned short* __restrict__ ctx) {
    __shared__ __align__(16) char smem[4 * 2048];  // per-wave 16x64 bf16 P-tile, XOR-swizzled
    const int bh = blockIdx.y, b = bh >> 3, h = bh & 7;
    const int wave = threadIdx.x >> 6, lane = threadIdx.x & 63;
    const int lr = lane & 15, lg = lane >> 4;
    const int qbase = blockIdx.x * 64 + wave * 16;

    // Q fragments (Q pre-scaled by 1/8 via WqT)
    const unsigned short* qp = Qh + ((size_t)bh * S + qbase + lr) * DK + lg * 8;
    bf16x8 a0 = *(const bf16x8*)qp;
    bf16x8 a1 = *(const bf16x8*)(qp + 32);

    const unsigned short* kb = Kh + (size_t)bh * S * DK;
    const unsigned short* vb = VhT + (size_t)bh * DK * S;
    const unsigned long long* mrow = mbits + (size_t)b * S * (S / 64);

    int qr[4];
#pragma unroll
    for (int j = 0; j < 4; j++) qr[j] = qbase + lg * 4 + j;

    // ---- pass A: softmax denominators (no max-sub needed: |scores| <~ 6) ----
    float l_[4] = {0.f, 0.f, 0.f, 0.f};
    for (int kc = 0; kc < S / 64; kc++) {
        unsigned long long wb[4];
#pragma unroll
        for (int j = 0; j < 4; j++) wb[j] = mrow[(size_t)qr[j] * (S / 64) + kc];
        f32x4 s[4];
#pragma unroll
        for (int t = 0; t < 4; t++) {
            const unsigned short* kp = kb + (size_t)(kc * 64 + t * 16 + lr) * DK + lg * 8;
            bf16x8 b0 = *(const bf16x8*)kp;
            bf16x8 b1 = *(const bf16x8*)(kp + 32);
            f32x4 z = {0.f, 0.f, 0.f, 0.f};
            z = MFMA(a0, b0, z);
            z = MFMA(a1, b1, z);
            s[t] = z;
        }
#pragma unroll
        for (int j = 0; j < 4; j++) {
            float rs = 0.f;
#pragma unroll
            for (int t = 0; t < 4; t++) {
                float sv = ((wb[j] >> (t * 16 + lr)) & 1ull) ? -1e9f : s[t][j];
                rs += __expf(sv);
            }
            l_[j] += redsum16(rs);
        }
    }
    float linv[4];
#pragma unroll
    for (int j = 0; j < 4; j++) linv[j] = 1.f / l_[j];

    // ---- pass B: recompute scores, write weights, PV ----
    f32x4 zero = {0.f, 0.f, 0.f, 0.f};
    f32x4 c[4] = {zero, zero, zero, zero};
    char* wt = smem + wave * 2048;
    float* wo = wout + (size_t)bh * S * S;

    for (int kc = 0; kc < S / 64; kc++) {
        unsigned long long wb[4];
#pragma unroll
        for (int j = 0; j < 4; j++) wb[j] = mrow[(size_t)qr[j] * (S / 64) + kc];
        f32x4 s[4];
#pragma unroll
        for (int t = 0; t < 4; t++) {
            const unsigned short* kp = kb + (size_t)(kc * 64 + t * 16 + lr) * DK + lg * 8;
            bf16x8 b0 = *(const bf16x8*)kp;
            bf16x8 b1 = *(const bf16x8*)(kp + 32);
            f32x4 z = {0.f, 0.f, 0.f, 0.f};
            z = MFMA(a0, b0, z);
            z = MFMA(a1, b1, z);
            s[t] = z;
        }
#pragma unroll
        for (int t = 0; t < 4; t++) {
            int kcol = kc * 64 + t * 16 + lr;
#pragma unroll
            for (int j = 0; j < 4; j++) {
                float sv = ((wb[j] >> (t * 16 + lr)) & 1ull) ? -1e9f : s[t][j];
                float w = __expf(sv) * linv[j];
                wo[(size_t)qr[j] * S + kcol] = w;
                int row = lg * 4 + j;
                int boff = ((t * 16 + lr) * 2) ^ ((row & 7) << 4);
                *(unsigned short*)(wt + row * 128 + boff) = f2bf(w);
            }
        }
        // P tile back as A-fragments (same-wave LDS roundtrip, swizzled read)
        bf16x8 pa0 = *(const bf16x8*)(wt + lr * 128 + ((lg * 16) ^ ((lr & 7) << 4)));
        bf16x8 pa1 = *(const bf16x8*)(wt + lr * 128 + ((64 + lg * 16) ^ ((lr & 7) << 4)));
#pragma unroll
        for (int dt = 0; dt < 4; dt++) {
            const unsigned short* vp = vb + (size_t)(dt * 16 + lr) * S + kc * 64 + lg * 8;
            bf16x8 v0 = *(const bf16x8*)vp;
            bf16x8 v1 = *(const bf16x8*)(vp + 32);
            c[dt] = MFMA(pa0, v0, c[dt]);
            c[dt] = MFMA(pa1, v1, c[dt]);
        }
    }
    // ctx store: [b][s][h*64+d] bf16
#pragma unroll
    for (int dt = 0; dt < 4; dt++)
#pragma unroll
        for (int j = 0; j < 4; j++)
            ctx[(size_t)(b * S + qr[j]) * NPROJ + h * 64 + dt * 16 + lr] = f2bf(c[dt][j]);
}

// ---------- output projection: ctx(bf16 4096x512) x WoT(bf16 768x512) -> fp32 out ----------
__global__ __launch_bounds__(256) void k_outproj(const unsigned short* __restrict__ A,
                                                 const unsigned short* __restrict__ BT,
                                                 float* __restrict__ out) {
    const int wave = threadIdx.x >> 6, lane = threadIdx.x & 63;
    const int lr = lane & 15, lg = lane >> 4;
    const int arow = blockIdx.x * 64 + wave * 16 + lr;

    f32x4 zero = {0.f, 0.f, 0.f, 0.f};
    f32x4 acc[4] = {zero, zero, zero, zero};

    const unsigned short* ap = A + (size_t)arow * NPROJ + lg * 8;
#pragma unroll 4
    for (int ks = 0; ks < NPROJ / 32; ks++) {
        bf16x8 a = *(const bf16x8*)(ap + ks * 32);
#pragma unroll
        for (int nt = 0; nt < 4; nt++) {
            const unsigned short* bp =
                BT + (size_t)(blockIdx.y * 64 + nt * 16 + lr) * NPROJ + ks * 32 + lg * 8;
            bf16x8 bb = *(const bf16x8*)bp;
            acc[nt] = MFMA(a, bb, acc[nt]);
        }
    }
#pragma unroll
    for (int nt = 0; nt < 4; nt++) {
        int col = blockIdx.y * 64 + nt * 16 + lr;
#pragma unroll
        for (int j = 0; j < 4; j++) {
            int r = blockIdx.x * 64 + wave * 16 + lg * 4 + j;
            out[(size_t)r * DM + col] = acc[nt][j];
        }
    }
}

extern "C" void kernel_launch(void* const* d_in, const int* in_sizes, int n_in,
                              void* d_out, int out_size, void* d_ws, size_t ws_size,
                              hipStream_t stream) {
    const float* q = (const float*)d_in[0];
    const float* k = (const float*)d_in[1];
    const float* v = (const float*)d_in[2];
    const unsigned char* mask = (const unsigned char*)d_in[3];
    const float* Wq = (const float*)d_in[4];
    const float* Wk = (const float*)d_in[5];
    const float* Wv = (const float*)d_in[6];
    const float* Wo = (const float*)d_in[7];

    float* out = (float*)d_out;
    float* weights = out + (size_t)BS * S * DM;  // 3,145,728

    char* ws = (char*)d_ws;
    const size_t WT_SZ = (size_t)NPROJ * DM * 2;       // 786432
    const size_t HEAD_SZ = (size_t)BH * S * DK * 2;    // 4 MiB
    unsigned short* WqT = (unsigned short*)(ws + 0 * WT_SZ);
    unsigned short* WkT = (unsigned short*)(ws + 1 * WT_SZ);
    unsigned short* WvT = (unsigned short*)(ws + 2 * WT_SZ);
    unsigned short* WoT = (unsigned short*)(ws + 3 * WT_SZ);
    char* base = ws + 4 * WT_SZ;
    unsigned short* Qh = (unsigned short*)(base + 0 * HEAD_SZ);
    unsigned short* Kh = (unsigned short*)(base + 1 * HEAD_SZ);
    unsigned short* Vh = (unsigned short*)(base + 2 * HEAD_SZ);
    unsigned short* VhT = (unsigned short*)(base + 3 * HEAD_SZ);
    unsigned short* ctx = (unsigned short*)(base + 4 * HEAD_SZ);
    unsigned long long* mbits = (unsigned long long*)(base + 5 * HEAD_SZ);
    // total ws use: 4*768K + 5*4M + 1M = 24 MiB
    if (ws_size < 4 * WT_SZ + 5 * HEAD_SZ + (size_t)BS * S * (S / 64) * 8) return;

    k_mask_bits<<<512, 256, 0, stream>>>(mask, mbits);
    dim3 tb(32, 8);
    k_transpose_w<<<dim3(NPROJ / 32, DM / 32), tb, 0, stream>>>(Wq, WqT, DM, NPROJ, 0.125f);
    k_transpose_w<<<dim3(NPROJ / 32, DM / 32), tb, 0, stream>>>(Wk, WkT, DM, NPROJ, 1.0f);
    k_transpose_w<<<dim3(NPROJ / 32, DM / 32), tb, 0, stream>>>(Wv, WvT, DM, NPROJ, 1.0f);
    k_transpose_w<<<dim3(DM / 32, NPROJ / 32), tb, 0, stream>>>(Wo, WoT, NPROJ, DM, 1.0f);

    k_proj<<<dim3(BS * S / 64, NPROJ / 64, 3), 256, 0, stream>>>(q, k, v, WqT, WkT, WvT, Qh, Kh, Vh);
    k_transpose_v<<<dim3(S / 64, BH), 256, 0, stream>>>(Vh, VhT);
    k_attn<<<dim3(S / 64, BH), 256, 0, stream>>>(Qh, Kh, VhT, mbits, weights, ctx);
    k_outproj<<<dim3(BS * S / 64, DM / 64), 256, 0, stream>>>(ctx, WoT, out);
}

// Round 2
// 234.425 us; speedup vs baseline: 1.4982x; 1.4982x over previous
//
#include <hip/hip_runtime.h>

#define DEV __device__ __forceinline__

typedef __attribute__((ext_vector_type(8))) short bf16x8;
typedef __attribute__((ext_vector_type(4))) float f32x4;

#define MFMA(a, b, c) __builtin_amdgcn_mfma_f32_16x16x32_bf16(a, b, c, 0, 0, 0)

// sizes (fixed problem)
#define BS 2
#define S 2048
#define DM 768
#define NH 8
#define DK 64
#define NPROJ 512   // NH*DK
#define BH 16       // BS*NH
#define KC 32       // S/64

DEV unsigned short f2bf(float f) {
    unsigned int u = __float_as_uint(f);
    unsigned int r = u + 0x7fffu + ((u >> 16) & 1u);
    return (unsigned short)(r >> 16);
}

DEV bf16x8 pack8(float4 f0, float4 f1) {
    bf16x8 r;
    r[0] = (short)f2bf(f0.x); r[1] = (short)f2bf(f0.y);
    r[2] = (short)f2bf(f0.z); r[3] = (short)f2bf(f0.w);
    r[4] = (short)f2bf(f1.x); r[5] = (short)f2bf(f1.y);
    r[6] = (short)f2bf(f1.z); r[7] = (short)f2bf(f1.w);
    return r;
}

DEV float redsum16(float v) {
    v += __shfl_xor(v, 1);
    v += __shfl_xor(v, 2);
    v += __shfl_xor(v, 4);
    v += __shfl_xor(v, 8);
    return v;
}

// ---------- mask (bool bytes) -> bitmask, 64 cols per u64 word ----------
__global__ __launch_bounds__(256) void k_mask_bits(const unsigned char* __restrict__ mask,
                                                   unsigned long long* __restrict__ bits) {
    int w = blockIdx.x * 256 + threadIdx.x;  // word index < BS*S*KC = 131072
    const unsigned long long* m8 = (const unsigned long long*)(mask + (size_t)w * 64);
    unsigned long long out = 0ull;
#pragma unroll
    for (int i = 0; i < 8; i++) {
        unsigned long long x = m8[i];
#pragma unroll
        for (int k = 0; k < 8; k++)
            if ((x >> (8 * k)) & 0xffull) out |= 1ull << (i * 8 + k);
    }
    bits[w] = out;
}

// ---------- W -> MFMA-B-fragment order: chunk[ks][nc][lane][8] = W[ks*32+(lane>>4)*8+e][nc*16+(lane&15)] ----------
__global__ __launch_bounds__(256) void k_wfrag(const float* __restrict__ W,
                                               unsigned short* __restrict__ out,
                                               int N, float scale) {
    int ks = blockIdx.x;
    int wave = threadIdx.x >> 6, lane = threadIdx.x & 63;
    int nc = blockIdx.y * 4 + wave;
    int lr = lane & 15, lg = lane >> 4;
    int NC = N >> 4;
    const float* src = W + (size_t)(ks * 32 + lg * 8) * N + nc * 16 + lr;
    bf16x8 v;
#pragma unroll
    for (int e = 0; e < 8; e++) v[e] = (short)f2bf(src[(size_t)e * N] * scale);
    *(bf16x8*)(out + ((size_t)(ks * NC + nc) * 64 + lane) * 8) = v;
}

// ---------- projection GEMM: A(fp32 4096x768) x Wfrag -> Qh natural / Kf,Vf frag-order ----------
__global__ __launch_bounds__(256, 2) void k_proj(
    const float* __restrict__ Aq, const float* __restrict__ Ak, const float* __restrict__ Av,
    const unsigned short* __restrict__ Wfq, const unsigned short* __restrict__ Wfk,
    const unsigned short* __restrict__ Wfv,
    unsigned short* __restrict__ Qh, unsigned short* __restrict__ Kf,
    unsigned short* __restrict__ Vf) {
    // XCD-aware decode: all 4 by-blocks of one (p,bx) land on the same XCD
    int lin = blockIdx.x;                    // 0..767
    int x = lin & 7, r = lin >> 3;           // r 0..95
    int by = r & 3;
    int pbx = (r >> 2) * 8 + x;              // 0..191
    int p = pbx >> 6, bx = pbx & 63;

    const float* A = (p == 0) ? Aq : ((p == 1) ? Ak : Av);
    const unsigned short* wf = (p == 0) ? Wfq : ((p == 1) ? Wfk : Wfv);

    const int wave = threadIdx.x >> 6, lane = threadIdx.x & 63;
    const int lr = lane & 15, lg = lane >> 4;
    const int arow = bx * 64 + wave * 16 + lr;

    f32x4 zero = {0.f, 0.f, 0.f, 0.f};
    f32x4 acc[8] = {zero, zero, zero, zero, zero, zero, zero, zero};

    const float* ap = A + (size_t)arow * DM + lg * 8;
    float4 f0 = *(const float4*)ap;
    float4 f1 = *(const float4*)(ap + 4);
#pragma unroll
    for (int ks = 0; ks < 24; ks++) {
        float4 g0, g1;
        if (ks < 23) {
            g0 = *(const float4*)(ap + (ks + 1) * 32);
            g1 = *(const float4*)(ap + (ks + 1) * 32 + 4);
        }
        bf16x8 a = pack8(f0, f1);
        const unsigned short* wp = wf + ((size_t)(ks * 32 + by * 8) * 64 + lane) * 8;
#pragma unroll
        for (int nt = 0; nt < 8; nt++) {
            bf16x8 b = *(const bf16x8*)(wp + (size_t)nt * 512);
            acc[nt] = MFMA(a, b, acc[nt]);
        }
        f0 = g0; f1 = g1;
    }

#pragma unroll
    for (int nt = 0; nt < 8; nt++) {
        int col = by * 128 + nt * 16 + lr;       // 0..511
        int h = col >> 6, dk = col & 63;
#pragma unroll
        for (int j = 0; j < 4; j++) {
            int sgl = bx * 64 + wave * 16 + lg * 4 + j;  // 0..4095
            int bb = sgl >> 11, srow = sgl & 2047;
            int bh = bb * NH + h;
            unsigned short val = f2bf(acc[nt][j]);
            if (p == 0) {
                Qh[((size_t)bh * S + srow) * DK + dk] = val;
            } else if (p == 1) {
                int kc = srow >> 6, t = (srow >> 4) & 3, lrk = srow & 15;
                int hh = dk >> 5, lgk = (dk >> 3) & 3, e = dk & 7;
                Kf[((((size_t)bh * KC + kc) * 4 + t) * 2 + hh) * 512 + (lgk * 16 + lrk) * 8 + e] = val;
            } else {
                int kc = srow >> 6, klo = srow & 63;
                int hh = klo >> 5, lgv = (klo >> 3) & 3, e = klo & 7;
                int dt = dk >> 4, lrv = dk & 15;
                Vf[((((size_t)bh * KC + kc) * 4 + dt) * 2 + hh) * 512 + (lgv * 16 + lrv) * 8 + e] = val;
            }
        }
    }
}

// ---------- fused attention: pass1 (QK^T, exp, l, PV unnormalized) + pass2 (weights) ----------
__global__ __launch_bounds__(256, 2) void k_attn(
    const unsigned short* __restrict__ Qh, const unsigned short* __restrict__ Kf,
    const unsigned short* __restrict__ Vf, const unsigned long long* __restrict__ mbits,
    float* __restrict__ wout, unsigned short* __restrict__ ctx) {
    __shared__ __align__(16) char smem[4 * 4480];
    // XCD-aware decode: bh pair {2x,2x+1} per XCD
    int lin = blockIdx.x;                 // 0..511
    int x = lin & 7, i = lin >> 3;        // i 0..63
    int bh = (x << 1) | (i >> 5), qc = i & 31;
    int b = bh >> 3, h = bh & 7;
    const int wave = threadIdx.x >> 6, lane = threadIdx.x & 63;
    const int lr = lane & 15, lg = lane >> 4;
    const int qbase = qc * 64 + wave * 16;

    const unsigned short* qp = Qh + ((size_t)bh * S + qbase + lr) * DK + lg * 8;
    bf16x8 a0 = *(const bf16x8*)qp;
    bf16x8 a1 = *(const bf16x8*)(qp + 32);

    const unsigned short* kb = Kf + (size_t)bh * KC * 4096;
    const unsigned short* vb = Vf + (size_t)bh * KC * 4096;
    const unsigned long long* mrow = mbits + (size_t)b * S * KC;

    int qr[4];
#pragma unroll
    for (int j = 0; j < 4; j++) qr[j] = qbase + lg * 4 + j;

    // ---- pass 1: scores -> exp -> {l accum, unnormalized PV} ----
    f32x4 zero = {0.f, 0.f, 0.f, 0.f};
    f32x4 c[4] = {zero, zero, zero, zero};
    float lsum[4] = {0.f, 0.f, 0.f, 0.f};
    char* wt = smem + wave * 4480;  // P-tile: first 2048B, XOR-swizzled

    bf16x8 kf[8];
    unsigned long long wb[4];
#pragma unroll
    for (int u = 0; u < 8; u++) kf[u] = *(const bf16x8*)(kb + (size_t)u * 512 + lane * 8);
#pragma unroll
    for (int j = 0; j < 4; j++) wb[j] = mrow[(size_t)qr[j] * KC];

    for (int kc = 0; kc < KC; kc++) {
        int nkc = (kc + 1 < KC) ? kc + 1 : kc;
        bf16x8 kn[8], vf[8];
        unsigned long long wbn[4];
#pragma unroll
        for (int u = 0; u < 8; u++)
            kn[u] = *(const bf16x8*)(kb + ((size_t)nkc * 8 + u) * 512 + lane * 8);
#pragma unroll
        for (int u = 0; u < 8; u++)
            vf[u] = *(const bf16x8*)(vb + ((size_t)kc * 8 + u) * 512 + lane * 8);
#pragma unroll
        for (int j = 0; j < 4; j++) wbn[j] = mrow[(size_t)qr[j] * KC + nkc];

        f32x4 s[4];
#pragma unroll
        for (int t = 0; t < 4; t++) {
            f32x4 z = {0.f, 0.f, 0.f, 0.f};
            z = MFMA(a0, kf[t * 2], z);
            z = MFMA(a1, kf[t * 2 + 1], z);
            s[t] = z;
        }
#pragma unroll
        for (int t = 0; t < 4; t++) {
#pragma unroll
            for (int j = 0; j < 4; j++) {
                float sv = ((wb[j] >> (t * 16 + lr)) & 1ull) ? -1e9f : s[t][j];
                float p = __expf(sv);
                lsum[j] += p;
                int row = lg * 4 + j;
                int boff = ((t * 16 + lr) * 2) ^ ((row & 7) << 4);
                *(unsigned short*)(wt + row * 128 + boff) = f2bf(p);
            }
        }
        bf16x8 pa0 = *(const bf16x8*)(wt + lr * 128 + ((lg * 16) ^ ((lr & 7) << 4)));
        bf16x8 pa1 = *(const bf16x8*)(wt + lr * 128 + ((64 + lg * 16) ^ ((lr & 7) << 4)));
#pragma unroll
        for (int dt = 0; dt < 4; dt++) {
            c[dt] = MFMA(pa0, vf[dt * 2], c[dt]);
            c[dt] = MFMA(pa1, vf[dt * 2 + 1], c[dt]);
        }
#pragma unroll
        for (int u = 0; u < 8; u++) kf[u] = kn[u];
#pragma unroll
        for (int j = 0; j < 4; j++) wb[j] = wbn[j];
    }

    float linv[4];
#pragma unroll
    for (int j = 0; j < 4; j++) linv[j] = 1.f / redsum16(lsum[j]);

    // ctx store: [b][s][h*64+d] bf16, scaled
#pragma unroll
    for (int dt = 0; dt < 4; dt++)
#pragma unroll
        for (int j = 0; j < 4; j++)
            ctx[((size_t)b * S + qr[j]) * NPROJ + h * 64 + dt * 16 + lr] = f2bf(c[dt][j] * linv[j]);

    // ---- pass 2: recompute scores, normalized fp32 weights via LDS transpose ----
    float* wo = wout + (size_t)bh * S * S;
    float* tile = (float*)(smem + wave * 4480);  // [16][69] fp32
#pragma unroll
    for (int u = 0; u < 8; u++) kf[u] = *(const bf16x8*)(kb + (size_t)u * 512 + lane * 8);
#pragma unroll
    for (int j = 0; j < 4; j++) wb[j] = mrow[(size_t)qr[j] * KC];

    for (int kc = 0; kc < KC; kc++) {
        int nkc = (kc + 1 < KC) ? kc + 1 : kc;
        bf16x8 kn[8];
        unsigned long long wbn[4];
#pragma unroll
        for (int u = 0; u < 8; u++)
            kn[u] = *(const bf16x8*)(kb + ((size_t)nkc * 8 + u) * 512 + lane * 8);
#pragma unroll
        for (int j = 0; j < 4; j++) wbn[j] = mrow[(size_t)qr[j] * KC + nkc];

        f32x4 s[4];
#pragma unroll
        for (int t = 0; t < 4; t++) {
            f32x4 z = {0.f, 0.f, 0.f, 0.f};
            z = MFMA(a0, kf[t * 2], z);
            z = MFMA(a1, kf[t * 2 + 1], z);
            s[t] = z;
        }
#pragma unroll
        for (int t = 0; t < 4; t++) {
#pragma unroll
            for (int j = 0; j < 4; j++) {
                float sv = ((wb[j] >> (t * 16 + lr)) & 1ull) ? -1e9f : s[t][j];
                tile[(lg * 4 + j) * 69 + t * 16 + lr] = __expf(sv) * linv[j];
            }
        }
        // read rows transposed, store float4 (wave-internal ordering, no barrier)
#pragma unroll
        for (int ii = 0; ii < 4; ii++) {
            float4 v4;
            v4.x = tile[lr * 69 + lg * 16 + ii * 4 + 0];
            v4.y = tile[lr * 69 + lg * 16 + ii * 4 + 1];
            v4.z = tile[lr * 69 + lg * 16 + ii * 4 + 2];
            v4.w = tile[lr * 69 + lg * 16 + ii * 4 + 3];
            *(float4*)(wo + (size_t)(qbase + lr) * S + kc * 64 + lg * 16 + ii * 4) = v4;
        }
#pragma unroll
        for (int u = 0; u < 8; u++) kf[u] = kn[u];
#pragma unroll
        for (int j = 0; j < 4; j++) wb[j] = wbn[j];
    }
}

// ---------- output projection: ctx(bf16 4096x512) x Wofrag -> fp32 out ----------
__global__ __launch_bounds__(256, 2) void k_outproj(const unsigned short* __restrict__ A,
                                                    const unsigned short* __restrict__ wfo,
                                                    float* __restrict__ out) {
    // XCD-aware decode: all 12 by-blocks of one bx on the same XCD
    int lin = blockIdx.x;                 // 0..767
    int x = lin & 7, r = lin >> 3;        // r 0..95
    int by = r >> 3, bxg = r & 7;         // by 0..11
    int bx = bxg * 8 + x;

    const int wave = threadIdx.x >> 6, lane = threadIdx.x & 63;
    const int lr = lane & 15, lg = lane >> 4;
    const int arow = bx * 64 + wave * 16 + lr;

    f32x4 zero = {0.f, 0.f, 0.f, 0.f};
    f32x4 acc[4] = {zero, zero, zero, zero};

    const unsigned short* ap = A + (size_t)arow * NPROJ + lg * 8;
    bf16x8 a = *(const bf16x8*)ap;
#pragma unroll
    for (int ks = 0; ks < 16; ks++) {
        bf16x8 an;
        if (ks < 15) an = *(const bf16x8*)(ap + (ks + 1) * 32);
#pragma unroll
        for (int nt = 0; nt < 4; nt++) {
            const unsigned short* bp = wfo + ((size_t)(ks * 48 + by * 4 + nt) * 64 + lane) * 8;
            bf16x8 bb = *(const bf16x8*)bp;
            acc[nt] = MFMA(a, bb, acc[nt]);
        }
        a = an;
    }
#pragma unroll
    for (int nt = 0; nt < 4; nt++) {
        int col = by * 64 + nt * 16 + lr;
#pragma unroll
        for (int j = 0; j < 4; j++) {
            int rr = bx * 64 + wave * 16 + lg * 4 + j;
            out[(size_t)rr * DM + col] = acc[nt][j];
        }
    }
}

extern "C" void kernel_launch(void* const* d_in, const int* in_sizes, int n_in,
                              void* d_out, int out_size, void* d_ws, size_t ws_size,
                              hipStream_t stream) {
    const float* q = (const float*)d_in[0];
    const float* k = (const float*)d_in[1];
    const float* v = (const float*)d_in[2];
    const unsigned char* mask = (const unsigned char*)d_in[3];
    const float* Wq = (const float*)d_in[4];
    const float* Wk = (const float*)d_in[5];
    const float* Wv = (const float*)d_in[6];
    const float* Wo = (const float*)d_in[7];

    float* out = (float*)d_out;
    float* weights = out + (size_t)BS * S * DM;

    char* ws = (char*)d_ws;
    const size_t WT_SZ = (size_t)393216 * 2;         // 768 KiB each
    const size_t HEAD_SZ = (size_t)BH * S * DK * 2;  // 4 MiB
    unsigned short* Wfq = (unsigned short*)(ws + 0 * WT_SZ);
    unsigned short* Wfk = (unsigned short*)(ws + 1 * WT_SZ);
    unsigned short* Wfv = (unsigned short*)(ws + 2 * WT_SZ);
    unsigned short* Wfo = (unsigned short*)(ws + 3 * WT_SZ);
    char* base = ws + 4 * WT_SZ;
    unsigned short* Qh = (unsigned short*)(base + 0 * HEAD_SZ);
    unsigned short* Kf = (unsigned short*)(base + 1 * HEAD_SZ);
    unsigned short* Vf = (unsigned short*)(base + 2 * HEAD_SZ);
    unsigned short* ctx = (unsigned short*)(base + 3 * HEAD_SZ);
    unsigned long long* mbits = (unsigned long long*)(base + 4 * HEAD_SZ);
    if (ws_size < 4 * WT_SZ + 4 * HEAD_SZ + (size_t)BS * S * KC * 8) return;  // 20 MiB

    k_mask_bits<<<512, 256, 0, stream>>>(mask, mbits);
    k_wfrag<<<dim3(24, 8), 256, 0, stream>>>(Wq, Wfq, NPROJ, 0.125f);
    k_wfrag<<<dim3(24, 8), 256, 0, stream>>>(Wk, Wfk, NPROJ, 1.0f);
    k_wfrag<<<dim3(24, 8), 256, 0, stream>>>(Wv, Wfv, NPROJ, 1.0f);
    k_wfrag<<<dim3(16, 12), 256, 0, stream>>>(Wo, Wfo, DM, 1.0f);

    k_proj<<<768, 256, 0, stream>>>(q, k, v, Wfq, Wfk, Wfv, Qh, Kf, Vf);
    k_attn<<<512, 256, 0, stream>>>(Qh, Kf, Vf, mbits, weights, ctx);
    k_outproj<<<768, 256, 0, stream>>>(ctx, Wfo, out);
}

// Round 3
// 233.953 us; speedup vs baseline: 1.5012x; 1.0020x over previous
//
#include <hip/hip_runtime.h>

#define DEV __device__ __forceinline__

typedef __attribute__((ext_vector_type(8))) short bf16x8;
typedef __attribute__((ext_vector_type(4))) float f32x4;

#define MFMA(a, b, c) __builtin_amdgcn_mfma_f32_16x16x32_bf16(a, b, c, 0, 0, 0)

// sizes (fixed problem)
#define BS 2
#define S 2048
#define DM 768
#define NH 8
#define DK 64
#define NPROJ 512   // NH*DK
#define BH 16       // BS*NH
#define KC 32       // S/64

DEV unsigned short f2bf(float f) {
    unsigned int u = __float_as_uint(f);
    unsigned int r = u + 0x7fffu + ((u >> 16) & 1u);
    return (unsigned short)(r >> 16);
}

DEV bf16x8 pack8(float4 f0, float4 f1) {
    bf16x8 r;
    r[0] = (short)f2bf(f0.x); r[1] = (short)f2bf(f0.y);
    r[2] = (short)f2bf(f0.z); r[3] = (short)f2bf(f0.w);
    r[4] = (short)f2bf(f1.x); r[5] = (short)f2bf(f1.y);
    r[6] = (short)f2bf(f1.z); r[7] = (short)f2bf(f1.w);
    return r;
}

DEV float redsum16(float v) {
    v += __shfl_xor(v, 1);
    v += __shfl_xor(v, 2);
    v += __shfl_xor(v, 4);
    v += __shfl_xor(v, 8);
    return v;
}

// ---------- mask (bool bytes) -> bitmask, 64 cols per u64 word ----------
__global__ __launch_bounds__(256) void k_mask_bits(const unsigned char* __restrict__ mask,
                                                   unsigned long long* __restrict__ bits) {
    int w = blockIdx.x * 256 + threadIdx.x;  // word index < BS*S*KC = 131072
    const unsigned long long* m8 = (const unsigned long long*)(mask + (size_t)w * 64);
    unsigned long long out = 0ull;
#pragma unroll
    for (int i = 0; i < 8; i++) {
        unsigned long long x = m8[i];
#pragma unroll
        for (int k = 0; k < 8; k++)
            if ((x >> (8 * k)) & 0xffull) out |= 1ull << (i * 8 + k);
    }
    bits[w] = out;
}

// ---------- all 4 W -> MFMA-B-fragment order, one launch ----------
__global__ __launch_bounds__(256) void k_wfrag_all(
    const float* __restrict__ Wq, const float* __restrict__ Wk, const float* __restrict__ Wv,
    const float* __restrict__ Wo, unsigned short* __restrict__ Oq,
    unsigned short* __restrict__ Ok, unsigned short* __restrict__ Ov,
    unsigned short* __restrict__ Oo) {
    int z = blockIdx.z;
    const float* W = (z == 0) ? Wq : ((z == 1) ? Wk : ((z == 2) ? Wv : Wo));
    unsigned short* out = (z == 0) ? Oq : ((z == 1) ? Ok : ((z == 2) ? Ov : Oo));
    int N = (z == 3) ? DM : NPROJ;
    float scale = (z == 0) ? 0.125f : 1.0f;

    int ks = blockIdx.x;
    int wave = threadIdx.x >> 6, lane = threadIdx.x & 63;
    int nc = blockIdx.y * 4 + wave;
    if (z < 3) { if (ks >= 24 || nc >= 32) return; }
    else       { if (ks >= 16) return; }
    int lr = lane & 15, lg = lane >> 4;
    int NC = N >> 4;
    const float* src = W + (size_t)(ks * 32 + lg * 8) * N + nc * 16 + lr;
    bf16x8 v;
#pragma unroll
    for (int e = 0; e < 8; e++) v[e] = (short)f2bf(src[(size_t)e * N] * scale);
    *(bf16x8*)(out + ((size_t)(ks * NC + nc) * 64 + lane) * 8) = v;
}

// ---------- projection GEMM: A(fp32 4096x768) x Wfrag -> Qh natural / Kf,Vf frag-order ----------
__global__ __launch_bounds__(256, 2) void k_proj(
    const float* __restrict__ Aq, const float* __restrict__ Ak, const float* __restrict__ Av,
    const unsigned short* __restrict__ Wfq, const unsigned short* __restrict__ Wfk,
    const unsigned short* __restrict__ Wfv,
    unsigned short* __restrict__ Qh, unsigned short* __restrict__ Kf,
    unsigned short* __restrict__ Vf) {
    // XCD-aware decode: all 4 by-blocks of one (p,bx) land on the same XCD
    int lin = blockIdx.x;                    // 0..767
    int x = lin & 7, r = lin >> 3;           // r 0..95
    int by = r & 3;
    int pbx = (r >> 2) * 8 + x;              // 0..191
    int p = pbx >> 6, bx = pbx & 63;

    const float* A = (p == 0) ? Aq : ((p == 1) ? Ak : Av);
    const unsigned short* wf = (p == 0) ? Wfq : ((p == 1) ? Wfk : Wfv);

    const int wave = threadIdx.x >> 6, lane = threadIdx.x & 63;
    const int lr = lane & 15, lg = lane >> 4;
    const int arow = bx * 64 + wave * 16 + lr;

    f32x4 zero = {0.f, 0.f, 0.f, 0.f};
    f32x4 acc[8] = {zero, zero, zero, zero, zero, zero, zero, zero};

    const float* ap = A + (size_t)arow * DM + lg * 8;
    float4 f0 = *(const float4*)ap;
    float4 f1 = *(const float4*)(ap + 4);
#pragma unroll
    for (int ks = 0; ks < 24; ks++) {
        float4 g0, g1;
        if (ks < 23) {
            g0 = *(const float4*)(ap + (ks + 1) * 32);
            g1 = *(const float4*)(ap + (ks + 1) * 32 + 4);
        }
        bf16x8 a = pack8(f0, f1);
        const unsigned short* wp = wf + ((size_t)(ks * 32 + by * 8) * 64 + lane) * 8;
#pragma unroll
        for (int nt = 0; nt < 8; nt++) {
            bf16x8 b = *(const bf16x8*)(wp + (size_t)nt * 512);
            acc[nt] = MFMA(a, b, acc[nt]);
        }
        f0 = g0; f1 = g1;
    }

#pragma unroll
    for (int nt = 0; nt < 8; nt++) {
        int col = by * 128 + nt * 16 + lr;       // 0..511
        int h = col >> 6, dk = col & 63;
#pragma unroll
        for (int j = 0; j < 4; j++) {
            int sgl = bx * 64 + wave * 16 + lg * 4 + j;  // 0..4095
            int bb = sgl >> 11, srow = sgl & 2047;
            int bh = bb * NH + h;
            unsigned short val = f2bf(acc[nt][j]);
            if (p == 0) {
                Qh[((size_t)bh * S + srow) * DK + dk] = val;
            } else if (p == 1) {
                int kc = srow >> 6, t = (srow >> 4) & 3, lrk = srow & 15;
                int hh = dk >> 5, lgk = (dk >> 3) & 3, e = dk & 7;
                Kf[((((size_t)bh * KC + kc) * 4 + t) * 2 + hh) * 512 + (lgk * 16 + lrk) * 8 + e] = val;
            } else {
                int kc = srow >> 6, klo = srow & 63;
                int hh = klo >> 5, lgv = (klo >> 3) & 3, e = klo & 7;
                int dt = dk >> 4, lrv = dk & 15;
                Vf[((((size_t)bh * KC + kc) * 4 + dt) * 2 + hh) * 512 + (lgv * 16 + lrv) * 8 + e] = val;
            }
        }
    }
}

// ---------- softmax denominators, K-split for occupancy ----------
__global__ __launch_bounds__(256, 4) void k_lsum(
    const unsigned short* __restrict__ Qh, const unsigned short* __restrict__ Kf,
    const unsigned long long* __restrict__ mbits, float* __restrict__ lpart) {
    // 2048 blocks: x(8 XCD) x [bh_lo(2) x qc(32) x ks(4)]
    int lin = blockIdx.x;
    int x = lin & 7, i = lin >> 3;          // i 0..255
    int bh = (x << 1) | (i >> 7);
    int i7 = i & 127;
    int qc = i7 >> 2, ks = i7 & 3;
    int b = bh >> 3;
    const int wave = threadIdx.x >> 6, lane = threadIdx.x & 63;
    const int lr = lane & 15, lg = lane >> 4;
    const int qbase = qc * 64 + wave * 16;

    const unsigned short* qp = Qh + ((size_t)bh * S + qbase + lr) * DK + lg * 8;
    bf16x8 a0 = *(const bf16x8*)qp;
    bf16x8 a1 = *(const bf16x8*)(qp + 32);

    const unsigned short* kb = Kf + (size_t)bh * KC * 4096;
    const unsigned long long* mrow = mbits + (size_t)b * S * KC;

    int qr[4];
#pragma unroll
    for (int j = 0; j < 4; j++) qr[j] = qbase + lg * 4 + j;

    float lsum[4] = {0.f, 0.f, 0.f, 0.f};
    for (int kk = 0; kk < 8; kk++) {
        int kc = ks * 8 + kk;
        bf16x8 kf[8];
        unsigned long long wb[4];
#pragma unroll
        for (int u = 0; u < 8; u++)
            kf[u] = *(const bf16x8*)(kb + ((size_t)kc * 8 + u) * 512 + lane * 8);
#pragma unroll
        for (int j = 0; j < 4; j++) wb[j] = mrow[(size_t)qr[j] * KC + kc];
        f32x4 s[4];
#pragma unroll
        for (int t = 0; t < 4; t++) {
            f32x4 z = {0.f, 0.f, 0.f, 0.f};
            z = MFMA(a0, kf[t * 2], z);
            z = MFMA(a1, kf[t * 2 + 1], z);
            s[t] = z;
        }
#pragma unroll
        for (int t = 0; t < 4; t++)
#pragma unroll
            for (int j = 0; j < 4; j++) {
                float sv = ((wb[j] >> (t * 16 + lr)) & 1ull) ? -1e9f : s[t][j];
                lsum[j] += __expf(sv);
            }
    }
#pragma unroll
    for (int j = 0; j < 4; j++) {
        float tot = redsum16(lsum[j]);
        if (lr == 0) lpart[((size_t)bh * S + qr[j]) * 4 + ks] = tot;
    }
}

// ---------- single-pass attention: recompute scores, write weights, PV ----------
__global__ __launch_bounds__(256, 2) void k_attn(
    const unsigned short* __restrict__ Qh, const unsigned short* __restrict__ Kf,
    const unsigned short* __restrict__ Vf, const unsigned long long* __restrict__ mbits,
    const float* __restrict__ lpart, float* __restrict__ wout,
    unsigned short* __restrict__ ctx) {
    __shared__ __align__(16) char smem[4 * 6464];  // per wave: fp32 tile [16][69] + bf16 P tile
    // XCD-aware decode: bh pair {2x,2x+1} per XCD
    int lin = blockIdx.x;                 // 0..511
    int x = lin & 7, i = lin >> 3;        // i 0..63
    int bh = (x << 1) | (i >> 5), qc = i & 31;
    int b = bh >> 3, h = bh & 7;
    const int wave = threadIdx.x >> 6, lane = threadIdx.x & 63;
    const int lr = lane & 15, lg = lane >> 4;
    const int qbase = qc * 64 + wave * 16;

    const unsigned short* qp = Qh + ((size_t)bh * S + qbase + lr) * DK + lg * 8;
    bf16x8 a0 = *(const bf16x8*)qp;
    bf16x8 a1 = *(const bf16x8*)(qp + 32);

    const unsigned short* kb = Kf + (size_t)bh * KC * 4096;
    const unsigned short* vb = Vf + (size_t)bh * KC * 4096;
    const unsigned long long* mrow = mbits + (size_t)b * S * KC;

    int qr[4];
#pragma unroll
    for (int j = 0; j < 4; j++) qr[j] = qbase + lg * 4 + j;

    float linv[4];
#pragma unroll
    for (int j = 0; j < 4; j++) {
        f32x4 lp = *(const f32x4*)(lpart + ((size_t)bh * S + qr[j]) * 4);
        linv[j] = 1.f / (lp[0] + lp[1] + lp[2] + lp[3]);
    }

    f32x4 zero = {0.f, 0.f, 0.f, 0.f};
    f32x4 c[4] = {zero, zero, zero, zero};
    char* wbase = smem + wave * 6464;
    float* tile = (float*)wbase;        // [16][69] fp32
    char* wt = wbase + 4416;            // 16x64 bf16, XOR-swizzled
    float* wo = wout + (size_t)bh * S * S;

    bf16x8 kf[8];
    unsigned long long wb[4];
#pragma unroll
    for (int u = 0; u < 8; u++) kf[u] = *(const bf16x8*)(kb + (size_t)u * 512 + lane * 8);
#pragma unroll
    for (int j = 0; j < 4; j++) wb[j] = mrow[(size_t)qr[j] * KC];

    for (int kc = 0; kc < KC; kc++) {
        int nkc = (kc + 1 < KC) ? kc + 1 : kc;
        bf16x8 kn[8], vf[8];
        unsigned long long wbn[4];
#pragma unroll
        for (int u = 0; u < 8; u++)
            kn[u] = *(const bf16x8*)(kb + ((size_t)nkc * 8 + u) * 512 + lane * 8);
#pragma unroll
        for (int u = 0; u < 8; u++)
            vf[u] = *(const bf16x8*)(vb + ((size_t)kc * 8 + u) * 512 + lane * 8);
#pragma unroll
        for (int j = 0; j < 4; j++) wbn[j] = mrow[(size_t)qr[j] * KC + nkc];

        f32x4 s[4];
        __builtin_amdgcn_s_setprio(1);
#pragma unroll
        for (int t = 0; t < 4; t++) {
            f32x4 z = {0.f, 0.f, 0.f, 0.f};
            z = MFMA(a0, kf[t * 2], z);
            z = MFMA(a1, kf[t * 2 + 1], z);
            s[t] = z;
        }
        __builtin_amdgcn_s_setprio(0);

        // normalized weights into both tiles
#pragma unroll
        for (int t = 0; t < 4; t++) {
#pragma unroll
            for (int j = 0; j < 4; j++) {
                float sv = ((wb[j] >> (t * 16 + lr)) & 1ull) ? -1e9f : s[t][j];
                float w = __expf(sv) * linv[j];
                int row = lg * 4 + j;
                tile[row * 69 + t * 16 + lr] = w;
                int boff = ((t * 16 + lr) * 2) ^ ((row & 7) << 4);
                *(unsigned short*)(wt + row * 128 + boff) = f2bf(w);
            }
        }
        // P tile as A-fragments (same-wave LDS roundtrip, swizzled read)
        bf16x8 pa0 = *(const bf16x8*)(wt + lr * 128 + ((lg * 16) ^ ((lr & 7) << 4)));
        bf16x8 pa1 = *(const bf16x8*)(wt + lr * 128 + ((64 + lg * 16) ^ ((lr & 7) << 4)));
        __builtin_amdgcn_s_setprio(1);
#pragma unroll
        for (int dt = 0; dt < 4; dt++) {
            c[dt] = MFMA(pa0, vf[dt * 2], c[dt]);
            c[dt] = MFMA(pa1, vf[dt * 2 + 1], c[dt]);
        }
        __builtin_amdgcn_s_setprio(0);
        // transposed readback, coalesced float4 weight stores
#pragma unroll
        for (int ii = 0; ii < 4; ii++) {
            float4 v4;
            v4.x = tile[lr * 69 + lg * 16 + ii * 4 + 0];
            v4.y = tile[lr * 69 + lg * 16 + ii * 4 + 1];
            v4.z = tile[lr * 69 + lg * 16 + ii * 4 + 2];
            v4.w = tile[lr * 69 + lg * 16 + ii * 4 + 3];
            *(float4*)(wo + (size_t)(qbase + lr) * S + kc * 64 + lg * 16 + ii * 4) = v4;
        }
#pragma unroll
        for (int u = 0; u < 8; u++) kf[u] = kn[u];
#pragma unroll
        for (int j = 0; j < 4; j++) wb[j] = wbn[j];
    }

    // ctx store: [b][s][h*64+d] bf16 (P already normalized)
#pragma unroll
    for (int dt = 0; dt < 4; dt++)
#pragma unroll
        for (int j = 0; j < 4; j++)
            ctx[((size_t)b * S + qr[j]) * NPROJ + h * 64 + dt * 16 + lr] = f2bf(c[dt][j]);
}

// ---------- output projection: ctx(bf16 4096x512) x Wofrag -> fp32 out ----------
__global__ __launch_bounds__(256, 2) void k_outproj(const unsigned short* __restrict__ A,
                                                    const unsigned short* __restrict__ wfo,
                                                    float* __restrict__ out) {
    // XCD-aware decode: all 12 by-blocks of one bx on the same XCD
    int lin = blockIdx.x;                 // 0..767
    int x = lin & 7, r = lin >> 3;        // r 0..95
    int by = r >> 3, bxg = r & 7;         // by 0..11
    int bx = bxg * 8 + x;

    const int wave = threadIdx.x >> 6, lane = threadIdx.x & 63;
    const int lr = lane & 15, lg = lane >> 4;
    const int arow = bx * 64 + wave * 16 + lr;

    f32x4 zero = {0.f, 0.f, 0.f, 0.f};
    f32x4 acc[4] = {zero, zero, zero, zero};

    const unsigned short* ap = A + (size_t)arow * NPROJ + lg * 8;
    bf16x8 a = *(const bf16x8*)ap;
#pragma unroll
    for (int ks = 0; ks < 16; ks++) {
        bf16x8 an;
        if (ks < 15) an = *(const bf16x8*)(ap + (ks + 1) * 32);
#pragma unroll
        for (int nt = 0; nt < 4; nt++) {
            const unsigned short* bp = wfo + ((size_t)(ks * 48 + by * 4 + nt) * 64 + lane) * 8;
            bf16x8 bb = *(const bf16x8*)bp;
            acc[nt] = MFMA(a, bb, acc[nt]);
        }
        a = an;
    }
#pragma unroll
    for (int nt = 0; nt < 4; nt++) {
        int col = by * 64 + nt * 16 + lr;
#pragma unroll
        for (int j = 0; j < 4; j++) {
            int rr = bx * 64 + wave * 16 + lg * 4 + j;
            out[(size_t)rr * DM + col] = acc[nt][j];
        }
    }
}

extern "C" void kernel_launch(void* const* d_in, const int* in_sizes, int n_in,
                              void* d_out, int out_size, void* d_ws, size_t ws_size,
                              hipStream_t stream) {
    const float* q = (const float*)d_in[0];
    const float* k = (const float*)d_in[1];
    const float* v = (const float*)d_in[2];
    const unsigned char* mask = (const unsigned char*)d_in[3];
    const float* Wq = (const float*)d_in[4];
    const float* Wk = (const float*)d_in[5];
    const float* Wv = (const float*)d_in[6];
    const float* Wo = (const float*)d_in[7];

    float* out = (float*)d_out;
    float* weights = out + (size_t)BS * S * DM;

    char* ws = (char*)d_ws;
    const size_t WT_SZ = (size_t)393216 * 2;         // 768 KiB each
    const size_t HEAD_SZ = (size_t)BH * S * DK * 2;  // 4 MiB
    unsigned short* Wfq = (unsigned short*)(ws + 0 * WT_SZ);
    unsigned short* Wfk = (unsigned short*)(ws + 1 * WT_SZ);
    unsigned short* Wfv = (unsigned short*)(ws + 2 * WT_SZ);
    unsigned short* Wfo = (unsigned short*)(ws + 3 * WT_SZ);
    char* base = ws + 4 * WT_SZ;
    unsigned short* Qh = (unsigned short*)(base + 0 * HEAD_SZ);
    unsigned short* Kf = (unsigned short*)(base + 1 * HEAD_SZ);
    unsigned short* Vf = (unsigned short*)(base + 2 * HEAD_SZ);
    unsigned short* ctx = (unsigned short*)(base + 3 * HEAD_SZ);
    unsigned long long* mbits = (unsigned long long*)(base + 4 * HEAD_SZ);
    float* lpart = (float*)(base + 5 * HEAD_SZ);     // [BH][S][4] f32 = 512 KiB
    if (ws_size < 4 * WT_SZ + 5 * HEAD_SZ + (size_t)BH * S * 4 * 4) return;

    k_mask_bits<<<512, 256, 0, stream>>>(mask, mbits);
    k_wfrag_all<<<dim3(24, 12, 4), 256, 0, stream>>>(Wq, Wk, Wv, Wo, Wfq, Wfk, Wfv, Wfo);
    k_proj<<<768, 256, 0, stream>>>(q, k, v, Wfq, Wfk, Wfv, Qh, Kf, Vf);
    k_lsum<<<2048, 256, 0, stream>>>(Qh, Kf, mbits, lpart);
    k_attn<<<512, 256, 0, stream>>>(Qh, Kf, Vf, mbits, lpart, weights, ctx);
    k_outproj<<<768, 256, 0, stream>>>(ctx, Wfo, out);
}